// Round 11
// baseline (71.968 us; speedup 1.0000x reference)
//
#include <hip/hip_runtime.h>

// GRU final-hidden: B=8192, T=2048, I=1, H=3.
// R11 = R10 math/layout (1 batch per lane, h lane-local, shared (r,z) rcp)
// with a 16-way time split: Q=128, K=64 warmup -> 2048 waves = 2/SIMD.
// R10 measured: wall 600 cyc/step = issue 350 + exposed chain-stall 250 at
// 1 wave/SIMD. Two co-resident waves fill each other's stalls (issue>=stall),
// so wall -> ~2*I per step-pair; per-wave steps drop 320 -> 192.

#define NL (-1.4426950408889634f)   // -log2(e): sigma(a)=rcp(1+exp2(NL*a))
#define TL ( 2.8853900817779268f)   // 2*log2(e): tanh(u)=1-2*rcp(1+exp2(TL*u))

typedef float f32x2 __attribute__((ext_vector_type(2)));

__device__ __forceinline__ float fexp2(float a) { return __builtin_amdgcn_exp2f(a); }
__device__ __forceinline__ float frcp(float a)  { return __builtin_amdgcn_rcpf(a); }

__global__ __launch_bounds__(64, 2) void gru_lane16(
    const float* __restrict__ x,      // [B,T] (I=1)
    const int*   __restrict__ lens,   // [B]
    const float* __restrict__ h0,     // [B,3]
    const float* __restrict__ W_ih,   // [9,1]
    const float* __restrict__ W_hh,   // [9,3]
    const float* __restrict__ b_ih,   // [9]
    const float* __restrict__ b_hh,   // [9]
    float*       __restrict__ out,    // [B,3]
    int B, int T)
{
    const int lane = threadIdx.x;          // block = 1 wave
    const int grp  = blockIdx.x >> 4;      // batch group (64 batches)
    const int q    = blockIdx.x & 15;      // time sixteenth
    const int batch = grp * 64 + lane;

    // ---- uniform weights (scalar loads -> SGPRs), pre-scaled to log2 domain.
    f32x2 wx_rz[3], w0_rz[3], w1_rz[3], w2_rz[3], cb_rz[3];
    float wxn[3], wn0[3], wn1[3], wn2[3], bni[3], bnh[3];
#pragma unroll
    for (int i = 0; i < 3; ++i) {
        wx_rz[i] = (f32x2){NL * W_ih[i], NL * W_ih[3 + i]};
        w0_rz[i] = (f32x2){NL * W_hh[i * 3 + 0], NL * W_hh[(3 + i) * 3 + 0]};
        w1_rz[i] = (f32x2){NL * W_hh[i * 3 + 1], NL * W_hh[(3 + i) * 3 + 1]};
        w2_rz[i] = (f32x2){NL * W_hh[i * 3 + 2], NL * W_hh[(3 + i) * 3 + 2]};
        cb_rz[i] = (f32x2){NL * (b_ih[i] + b_hh[i]), NL * (b_ih[3 + i] + b_hh[3 + i])};
        wxn[i] = TL * W_ih[6 + i];
        wn0[i] = TL * W_hh[(6 + i) * 3 + 0];
        wn1[i] = TL * W_hh[(6 + i) * 3 + 1];
        wn2[i] = TL * W_hh[(6 + i) * 3 + 2];
        bni[i] = TL * b_ih[6 + i];
        bnh[i] = TL * b_hh[6 + i];
    }

    const int lenm1 = lens[batch] - 1;

    // wave-wide max length over the 64 batches, rounded up to multiple of 8
    int wmax = lenm1 + 1;
#pragma unroll
    for (int off = 32; off >= 1; off >>= 1)
        wmax = max(wmax, __shfl_xor(wmax, off));
    wmax = (wmax + 7) & ~7;

    const int Q = T >> 4;                  // 128
    const int K = 64;                      // warmup (exact at R9/R10)

    const int ts = (q == 0) ? 0 : q * Q - K;
    int te = (q + 1) * Q; if (te > wmax) te = wmax;   // may be <= ts -> skip

    float hv0, hv1, hv2;
    if (q == 0) { hv0 = h0[batch * 3 + 0]; hv1 = h0[batch * 3 + 1]; hv2 = h0[batch * 3 + 2]; }
    else        { hv0 = 0.0f; hv1 = 0.0f; hv2 = 0.0f; }
    float hs0 = hv0, hs1 = hv1, hs2 = hv2;             // saved at t == lenm1

    const float* xp = x + (long long)batch * T;
    // 16-step-deep prefetch pipeline
    float4 c0 = *reinterpret_cast<const float4*>(xp + ts);
    float4 c1 = *reinterpret_cast<const float4*>(xp + ts + 4);
    const int t1 = ts + 8 > T - 8 ? T - 8 : ts + 8;
    float4 n0 = *reinterpret_cast<const float4*>(xp + t1);
    float4 n1 = *reinterpret_cast<const float4*>(xp + t1 + 4);

    for (int t0 = ts; t0 < te; t0 += 8) {
        int ta = t0 + 16; if (ta > T - 8) ta = T - 8;   // 2 iters ahead
        float4 f0 = *reinterpret_cast<const float4*>(xp + ta);
        float4 f1 = *reinterpret_cast<const float4*>(xp + ta + 4);

        const float xs[8] = {c0.x, c0.y, c0.z, c0.w, c1.x, c1.y, c1.z, c1.w};

#pragma unroll
        for (int k = 0; k < 8; ++k) {
            const float xk = xs[k];
            const f32x2 xp2 = {xk, xk};
            const f32x2 h0p = {hv0, hv0};
            const f32x2 h1p = {hv1, hv1};
            const f32x2 h2p = {hv2, hv2};

            // (sr,sz) packed dots; all three components independent (ILP)
            f32x2 s0 = __builtin_elementwise_fma(xp2, wx_rz[0], cb_rz[0]);
            f32x2 s1 = __builtin_elementwise_fma(xp2, wx_rz[1], cb_rz[1]);
            f32x2 s2 = __builtin_elementwise_fma(xp2, wx_rz[2], cb_rz[2]);
            s0 = __builtin_elementwise_fma(h0p, w0_rz[0], s0);
            s1 = __builtin_elementwise_fma(h0p, w0_rz[1], s1);
            s2 = __builtin_elementwise_fma(h0p, w0_rz[2], s2);
            s0 = __builtin_elementwise_fma(h1p, w1_rz[0], s0);
            s1 = __builtin_elementwise_fma(h1p, w1_rz[1], s1);
            s2 = __builtin_elementwise_fma(h1p, w1_rz[2], s2);
            s0 = __builtin_elementwise_fma(h2p, w2_rz[0], s0);
            s1 = __builtin_elementwise_fma(h2p, w2_rz[1], s1);
            s2 = __builtin_elementwise_fma(h2p, w2_rz[2], s2);

            // n-gate dots (scalar)
            float hg0 = fmaf(wn0[0], hv0, bnh[0]); hg0 = fmaf(wn1[0], hv1, hg0); hg0 = fmaf(wn2[0], hv2, hg0);
            float hg1 = fmaf(wn0[1], hv0, bnh[1]); hg1 = fmaf(wn1[1], hv1, hg1); hg1 = fmaf(wn2[1], hv2, hg1);
            float hg2 = fmaf(wn0[2], hv0, bnh[2]); hg2 = fmaf(wn1[2], hv1, hg2); hg2 = fmaf(wn2[2], hv2, hg2);
            const float bxn0 = fmaf(xk, wxn[0], bni[0]);
            const float bxn1 = fmaf(xk, wxn[1], bni[1]);
            const float bxn2 = fmaf(xk, wxn[2], bni[2]);

            // exp2 of all six (r,z) logits
            const float Ar0 = fexp2(s0.x), Az0 = fexp2(s0.y);
            const float Ar1 = fexp2(s1.x), Az1 = fexp2(s1.y);
            const float Ar2 = fexp2(s2.x), Az2 = fexp2(s2.y);

            // shared reciprocal per component: r=(1+Az)/D, z=(1+Ar)/D
            const float pr0 = Ar0 + 1.0f, pz0 = Az0 + 1.0f;
            const float pr1 = Ar1 + 1.0f, pz1 = Az1 + 1.0f;
            const float pr2 = Ar2 + 1.0f, pz2 = Az2 + 1.0f;
            const float rd0 = frcp(pr0 * pz0);
            const float rd1 = frcp(pr1 * pz1);
            const float rd2 = frcp(pr2 * pz2);
            const float r0 = pz0 * rd0, z0 = pr0 * rd0;
            const float r1 = pz1 * rd1, z1 = pr1 * rd1;
            const float r2 = pz2 * rd2, z2 = pr2 * rd2;

            // tanh stage: v = r*hg + bxn (log2-domain), u = 1/(1+2^v)
            const float v0 = fmaf(r0, hg0, bxn0);
            const float v1 = fmaf(r1, hg1, bxn1);
            const float v2 = fmaf(r2, hg2, bxn2);
            const float u0 = frcp(fexp2(v0) + 1.0f);
            const float u1 = frcp(fexp2(v1) + 1.0f);
            const float u2 = frcp(fexp2(v2) + 1.0f);

            // h' = (1-z)*(1-2u) + z*h = ac + bc*u ; ac=z*(h-1)+1, bc=2z-2
            const float ac0 = fmaf(z0, hv0 - 1.0f, 1.0f), bc0 = fmaf(2.0f, z0, -2.0f);
            const float ac1 = fmaf(z1, hv1 - 1.0f, 1.0f), bc1 = fmaf(2.0f, z1, -2.0f);
            const float ac2 = fmaf(z2, hv2 - 1.0f, 1.0f), bc2 = fmaf(2.0f, z2, -2.0f);
            hv0 = fmaf(bc0, u0, ac0);
            hv1 = fmaf(bc1, u1, ac1);
            hv2 = fmaf(bc2, u2, ac2);

            const bool save = (t0 + k) == lenm1;       // off-chain save
            hs0 = save ? hv0 : hs0;
            hs1 = save ? hv1 : hs1;
            hs2 = save ? hv2 : hs2;
        }
        c0 = n0; c1 = n1; n0 = f0; n1 = f1;
    }

    // disjoint writers: sixteenth q owns lenm1 in [q*Q, (q+1)*Q)
    if (lenm1 >= q * Q && lenm1 < (q + 1) * Q) {
        out[batch * 3 + 0] = frcp(fexp2(NL * hs0) + 1.0f);
        out[batch * 3 + 1] = frcp(fexp2(NL * hs1) + 1.0f);
        out[batch * 3 + 2] = frcp(fexp2(NL * hs2) + 1.0f);
    }
}

extern "C" void kernel_launch(void* const* d_in, const int* in_sizes, int n_in,
                              void* d_out, int out_size, void* d_ws, size_t ws_size,
                              hipStream_t stream) {
    const float* x    = (const float*)d_in[0];
    const int*   lens = (const int*)  d_in[1];
    const float* h0   = (const float*)d_in[2];
    const float* W_ih = (const float*)d_in[3];
    const float* W_hh = (const float*)d_in[4];
    const float* b_ih = (const float*)d_in[5];
    const float* b_hh = (const float*)d_in[6];
    float* out = (float*)d_out;

    const int B = in_sizes[1];              // seq_lengths is [B]
    const int T = in_sizes[0] / B;          // x is [B,T,1]

    gru_lane16<<<(B / 64) * 16, 64, 0, stream>>>(x, lens, h0, W_ih, W_hh, b_ih, b_hh, out, B, T);
}

// Round 12
// 64.591 us; speedup vs baseline: 1.1142x; 1.1142x over previous
//
#include <hip/hip_runtime.h>

// GRU final-hidden: B=8192, T=2048, I=1, H=3.
// R12: TWO batches per lane, all state/ALU packed as f32x2 (v_pk_fma_f32) --
// deterministic in-stream stall filling (R8/R11 showed HW 2-wave interleave
// fills poorly; R4's scalar 2-chain failed under the 32-VGPR cap). n=16 time
// split (Q=128, K=64 warmup) -> 1024 waves = 1/SIMD. Trans cut to 11/batch-
// step via all-shared rcp: one rcp for all six (r,z) gates, one for 3 tanhs.

#define NL (-1.4426950408889634f)   // -log2(e)
#define TL ( 2.8853900817779268f)   // 2*log2(e)

typedef float f32x2 __attribute__((ext_vector_type(2)));

__device__ __forceinline__ float fexp2(float a) { return __builtin_amdgcn_exp2f(a); }
__device__ __forceinline__ float frcp(float a)  { return __builtin_amdgcn_rcpf(a); }
__device__ __forceinline__ f32x2 pfma(f32x2 a, f32x2 b, f32x2 c) { return __builtin_elementwise_fma(a, b, c); }

__global__ __launch_bounds__(64, 1) void gru_pk2(
    const float* __restrict__ x,      // [B,T] (I=1)
    const int*   __restrict__ lens,   // [B]
    const float* __restrict__ h0,     // [B,3]
    const float* __restrict__ W_ih,   // [9,1]
    const float* __restrict__ W_hh,   // [9,3]
    const float* __restrict__ b_ih,   // [9]
    const float* __restrict__ b_hh,   // [9]
    float*       __restrict__ out,    // [B,3]
    int B, int T)
{
    const int lane = threadIdx.x;          // block = 1 wave
    const int grp  = blockIdx.x >> 4;      // batch group (128 batches)
    const int q    = blockIdx.x & 15;      // time sixteenth
    const int bA = grp * 128 + lane;
    const int bB = bA + 64;

    // ---- uniform weights, log2-prescaled, duplicated {w,w} for pk ops ----
    f32x2 wxr[3], wxz[3], wr0[3], wr1[3], wr2[3], wz0[3], wz1[3], wz2[3];
    f32x2 cbr[3], cbz[3], wxn[3], wn0[3], wn1[3], wn2[3], bni[3], bnh[3];
#pragma unroll
    for (int i = 0; i < 3; ++i) {
        float t;
        t = NL * W_ih[i];              wxr[i] = (f32x2){t, t};
        t = NL * W_ih[3 + i];          wxz[i] = (f32x2){t, t};
        t = NL * W_hh[i * 3 + 0];      wr0[i] = (f32x2){t, t};
        t = NL * W_hh[i * 3 + 1];      wr1[i] = (f32x2){t, t};
        t = NL * W_hh[i * 3 + 2];      wr2[i] = (f32x2){t, t};
        t = NL * W_hh[(3 + i) * 3 + 0]; wz0[i] = (f32x2){t, t};
        t = NL * W_hh[(3 + i) * 3 + 1]; wz1[i] = (f32x2){t, t};
        t = NL * W_hh[(3 + i) * 3 + 2]; wz2[i] = (f32x2){t, t};
        t = NL * (b_ih[i] + b_hh[i]);          cbr[i] = (f32x2){t, t};
        t = NL * (b_ih[3 + i] + b_hh[3 + i]);  cbz[i] = (f32x2){t, t};
        t = TL * W_ih[6 + i];          wxn[i] = (f32x2){t, t};
        t = TL * W_hh[(6 + i) * 3 + 0]; wn0[i] = (f32x2){t, t};
        t = TL * W_hh[(6 + i) * 3 + 1]; wn1[i] = (f32x2){t, t};
        t = TL * W_hh[(6 + i) * 3 + 2]; wn2[i] = (f32x2){t, t};
        t = TL * b_ih[6 + i];          bni[i] = (f32x2){t, t};
        t = TL * b_hh[6 + i];          bnh[i] = (f32x2){t, t};
    }
    const f32x2 one  = {1.0f, 1.0f};
    const f32x2 two  = {2.0f, 2.0f};
    const f32x2 mtwo = {-2.0f, -2.0f};

    const int lenm1A = lens[bA] - 1;
    const int lenm1B = lens[bB] - 1;

    // wave-wide max length over the 128 batches, rounded up to multiple of 8
    int wmax = max(lenm1A, lenm1B) + 1;
#pragma unroll
    for (int off = 32; off >= 1; off >>= 1)
        wmax = max(wmax, __shfl_xor(wmax, off));
    wmax = (wmax + 7) & ~7;

    const int Q = T >> 4;                  // 128
    const int K = 64;                      // warmup (exact at R9/R10/R11)

    const int ts = (q == 0) ? 0 : q * Q - K;
    int te = (q + 1) * Q; if (te > wmax) te = wmax;   // may be <= ts -> skip

    f32x2 hv0, hv1, hv2;
    if (q == 0) {
        hv0 = (f32x2){h0[bA * 3 + 0], h0[bB * 3 + 0]};
        hv1 = (f32x2){h0[bA * 3 + 1], h0[bB * 3 + 1]};
        hv2 = (f32x2){h0[bA * 3 + 2], h0[bB * 3 + 2]};
    } else {
        hv0 = (f32x2){0.0f, 0.0f}; hv1 = hv0; hv2 = hv0;
    }
    f32x2 hs0 = hv0, hs1 = hv1, hs2 = hv2;             // saved at t == lenm1

    const float* xpA = x + (long long)bA * T;
    const float* xpB = x + (long long)bB * T;
    // 16-step-deep prefetch pipeline, two streams
    float4 c0A = *reinterpret_cast<const float4*>(xpA + ts);
    float4 c1A = *reinterpret_cast<const float4*>(xpA + ts + 4);
    float4 c0B = *reinterpret_cast<const float4*>(xpB + ts);
    float4 c1B = *reinterpret_cast<const float4*>(xpB + ts + 4);
    const int t1 = ts + 8 > T - 8 ? T - 8 : ts + 8;
    float4 n0A = *reinterpret_cast<const float4*>(xpA + t1);
    float4 n1A = *reinterpret_cast<const float4*>(xpA + t1 + 4);
    float4 n0B = *reinterpret_cast<const float4*>(xpB + t1);
    float4 n1B = *reinterpret_cast<const float4*>(xpB + t1 + 4);

    for (int t0 = ts; t0 < te; t0 += 8) {
        int ta = t0 + 16; if (ta > T - 8) ta = T - 8;   // 2 iters ahead
        float4 f0A = *reinterpret_cast<const float4*>(xpA + ta);
        float4 f1A = *reinterpret_cast<const float4*>(xpA + ta + 4);
        float4 f0B = *reinterpret_cast<const float4*>(xpB + ta);
        float4 f1B = *reinterpret_cast<const float4*>(xpB + ta + 4);

        const float xsA[8] = {c0A.x, c0A.y, c0A.z, c0A.w, c1A.x, c1A.y, c1A.z, c1A.w};
        const float xsB[8] = {c0B.x, c0B.y, c0B.z, c0B.w, c1B.x, c1B.y, c1B.z, c1B.w};

#pragma unroll
        for (int k = 0; k < 8; ++k) {
            const f32x2 xv = {xsA[k], xsB[k]};

            // packed gate dots (batch A in .x, batch B in .y)
            f32x2 sr[3], sz[3], hg[3], bxn[3];
#pragma unroll
            for (int i = 0; i < 3; ++i) {
                sr[i] = pfma(xv, wxr[i], cbr[i]);
                sz[i] = pfma(xv, wxz[i], cbz[i]);
                sr[i] = pfma(hv0, wr0[i], sr[i]);
                sz[i] = pfma(hv0, wz0[i], sz[i]);
                sr[i] = pfma(hv1, wr1[i], sr[i]);
                sz[i] = pfma(hv1, wz1[i], sz[i]);
                sr[i] = pfma(hv2, wr2[i], sr[i]);
                sz[i] = pfma(hv2, wz2[i], sz[i]);
                hg[i] = pfma(hv0, wn0[i], bnh[i]);
                hg[i] = pfma(hv1, wn1[i], hg[i]);
                hg[i] = pfma(hv2, wn2[i], hg[i]);
                bxn[i] = pfma(xv, wxn[i], bni[i]);
            }

            // exp2 of all six (r,z) logits per batch (12 scalar exp2)
            f32x2 pr[3], pz[3];
#pragma unroll
            for (int i = 0; i < 3; ++i) {
                pr[i] = (f32x2){fexp2(sr[i].x), fexp2(sr[i].y)} + one;
                pz[i] = (f32x2){fexp2(sz[i].x), fexp2(sz[i].y)} + one;
            }

            // single shared reciprocal for all six gates (per batch)
            const f32x2 m0 = pr[0] * pz[0];
            const f32x2 m1 = pr[1] * pz[1];
            const f32x2 m2 = pr[2] * pz[2];
            const f32x2 m01 = m0 * m1, m12 = m1 * m2, m02 = m0 * m2;
            const f32x2 D  = m01 * m2;
            const f32x2 rd = {frcp(D.x), frcp(D.y)};
            const f32x2 inv0 = rd * m12, inv1 = rd * m02, inv2 = rd * m01;

            f32x2 r[3], z[3];
            r[0] = pz[0] * inv0; z[0] = pr[0] * inv0;
            r[1] = pz[1] * inv1; z[1] = pr[1] * inv1;
            r[2] = pz[2] * inv2; z[2] = pr[2] * inv2;

            // tanh stage: v_i = r_i*hg_i + bxn_i ; u_i = 1/(1+2^v_i), shared rcp
            f32x2 p[3];
#pragma unroll
            for (int i = 0; i < 3; ++i) {
                const f32x2 v = pfma(r[i], hg[i], bxn[i]);
                p[i] = (f32x2){fexp2(v.x), fexp2(v.y)} + one;
            }
            const f32x2 p01 = p[0] * p[1], p12 = p[1] * p[2], p02 = p[0] * p[2];
            const f32x2 Dp  = p01 * p[2];
            const f32x2 rdp = {frcp(Dp.x), frcp(Dp.y)};
            const f32x2 u0 = rdp * p12, u1 = rdp * p02, u2 = rdp * p01;

            // h' = ac + bc*u ; ac = z*(h-1)+1, bc = 2z-2
            const f32x2 ac0 = pfma(z[0], hv0 - one, one), bc0 = pfma(two, z[0], mtwo);
            const f32x2 ac1 = pfma(z[1], hv1 - one, one), bc1 = pfma(two, z[1], mtwo);
            const f32x2 ac2 = pfma(z[2], hv2 - one, one), bc2 = pfma(two, z[2], mtwo);
            hv0 = pfma(bc0, u0, ac0);
            hv1 = pfma(bc1, u1, ac1);
            hv2 = pfma(bc2, u2, ac2);

            // off-chain save at each batch's final step
            const bool saveA = (t0 + k) == lenm1A;
            const bool saveB = (t0 + k) == lenm1B;
            hs0.x = saveA ? hv0.x : hs0.x;  hs0.y = saveB ? hv0.y : hs0.y;
            hs1.x = saveA ? hv1.x : hs1.x;  hs1.y = saveB ? hv1.y : hs1.y;
            hs2.x = saveA ? hv2.x : hs2.x;  hs2.y = saveB ? hv2.y : hs2.y;
        }
        c0A = n0A; c1A = n1A; n0A = f0A; n1A = f1A;
        c0B = n0B; c1B = n1B; n0B = f0B; n1B = f1B;
    }

    // disjoint writers: sixteenth q owns lenm1 in [q*Q, (q+1)*Q)
    if (lenm1A >= q * Q && lenm1A < (q + 1) * Q) {
        out[bA * 3 + 0] = frcp(fexp2(NL * hs0.x) + 1.0f);
        out[bA * 3 + 1] = frcp(fexp2(NL * hs1.x) + 1.0f);
        out[bA * 3 + 2] = frcp(fexp2(NL * hs2.x) + 1.0f);
    }
    if (lenm1B >= q * Q && lenm1B < (q + 1) * Q) {
        out[bB * 3 + 0] = frcp(fexp2(NL * hs0.y) + 1.0f);
        out[bB * 3 + 1] = frcp(fexp2(NL * hs1.y) + 1.0f);
        out[bB * 3 + 2] = frcp(fexp2(NL * hs2.y) + 1.0f);
    }
}

extern "C" void kernel_launch(void* const* d_in, const int* in_sizes, int n_in,
                              void* d_out, int out_size, void* d_ws, size_t ws_size,
                              hipStream_t stream) {
    const float* x    = (const float*)d_in[0];
    const int*   lens = (const int*)  d_in[1];
    const float* h0   = (const float*)d_in[2];
    const float* W_ih = (const float*)d_in[3];
    const float* W_hh = (const float*)d_in[4];
    const float* b_ih = (const float*)d_in[5];
    const float* b_hh = (const float*)d_in[6];
    float* out = (float*)d_out;

    const int B = in_sizes[1];              // seq_lengths is [B]
    const int T = in_sizes[0] / B;          // x is [B,T,1]

    gru_pk2<<<(B / 128) * 16, 64, 0, stream>>>(x, lens, h0, W_ih, W_hh, b_ih, b_hh, out, B, T);
}